// Round 1
// baseline (167.076 us; speedup 1.0000x reference)
//
#include <hip/hip_runtime.h>
#include <hip/hip_bf16.h>

// Problem constants (from reference setup_inputs):
//   B=32, L=256, K=8, E=768, V=50000 ; M = B*L = 8192
// inputs: hidden [M,E] f32, similar_words [M,K] int32, word2vec [V,E] f32, weight [E,E] f32
// out:    [M,E] f32

#define GM_BM 128
#define GM_BN 64
#define GM_BK 16
#define GM_TM 8
#define GM_TN 4

// q_proj[m,f] = sum_e hidden[m,e] * weight[e,f]
__global__ __launch_bounds__(256) void gemm_qproj(const float* __restrict__ A,
                                                  const float* __restrict__ B,
                                                  float* __restrict__ C,
                                                  int M, int N, int K) {
    __shared__ float As[GM_BK][GM_BM];   // A tile, transposed (k-major)
    __shared__ float Bs[GM_BK][GM_BN];

    const int tid = threadIdx.x;
    const int tx = tid & 15;   // 16 threads over N, TN=4 -> 64 cols
    const int ty = tid >> 4;   // 16 threads over M, TM=8 -> 128 rows
    const int bm = blockIdx.x * GM_BM;
    const int bn = blockIdx.y * GM_BN;

    float acc[GM_TM][GM_TN];
#pragma unroll
    for (int i = 0; i < GM_TM; ++i)
#pragma unroll
        for (int j = 0; j < GM_TN; ++j) acc[i][j] = 0.f;

    for (int k0 = 0; k0 < K; k0 += GM_BK) {
        // Stage A tile: 128x16 f32 = 512 float4, 2 per thread; store transposed.
#pragma unroll
        for (int i = 0; i < 2; ++i) {
            int idx = tid * 2 + i;        // 0..511
            int row = idx >> 2;           // 0..127
            int c4  = idx & 3;            // 0..3
            float4 v = *(const float4*)(A + (size_t)(bm + row) * K + k0 + c4 * 4);
            As[c4 * 4 + 0][row] = v.x;
            As[c4 * 4 + 1][row] = v.y;
            As[c4 * 4 + 2][row] = v.z;
            As[c4 * 4 + 3][row] = v.w;
        }
        // Stage B tile: 16x64 f32 = 256 float4, 1 per thread; direct layout.
        {
            int row = tid >> 4;           // 0..15
            int c4  = tid & 15;           // 0..15
            float4 v = *(const float4*)(B + (size_t)(k0 + row) * N + bn + c4 * 4);
            *(float4*)&Bs[row][c4 * 4] = v;
        }
        __syncthreads();

#pragma unroll
        for (int k = 0; k < GM_BK; ++k) {
            float a[GM_TM], b[GM_TN];
#pragma unroll
            for (int i = 0; i < GM_TM; ++i) a[i] = As[k][ty * GM_TM + i];
#pragma unroll
            for (int j = 0; j < GM_TN; ++j) b[j] = Bs[k][tx * GM_TN + j];
#pragma unroll
            for (int i = 0; i < GM_TM; ++i)
#pragma unroll
                for (int j = 0; j < GM_TN; ++j) acc[i][j] += a[i] * b[j];
        }
        __syncthreads();
    }

#pragma unroll
    for (int i = 0; i < GM_TM; ++i) {
        float4 v;
        v.x = acc[i][0]; v.y = acc[i][1]; v.z = acc[i][2]; v.w = acc[i][3];
        *(float4*)(C + (size_t)(bm + ty * GM_TM + i) * N + bn + tx * GM_TN) = v;
    }
}

// One wave per (b,l) row: gather 8 w2v rows, dot with q_proj row, softmax(8),
// weighted sum -> out row. 4 waves (4 rows) per 256-thread block.
__global__ __launch_bounds__(256) void attn_fused(const float* __restrict__ qproj,
                                                  const int* __restrict__ sws,
                                                  const float* __restrict__ w2v,
                                                  float* __restrict__ out) {
    const int wave = threadIdx.x >> 6;
    const int lane = threadIdx.x & 63;
    const size_t row = (size_t)blockIdx.x * 4 + wave;   // 0..8191

    // Load q row: 768 f32 = 192 float4, 3 per lane, coalesced.
    const float4* q4 = (const float4*)(qproj + row * 768);
    float4 q[3];
#pragma unroll
    for (int j = 0; j < 3; ++j) q[j] = q4[j * 64 + lane];

    // Gather 8 similar-word rows; keep in registers; per-lane partial dots.
    float4 ks[8][3];
    float dot[8];
#pragma unroll
    for (int k = 0; k < 8; ++k) {
        int id = sws[row * 8 + k];
        const float4* kp = (const float4*)(w2v + (size_t)id * 768);
        float d = 0.f;
#pragma unroll
        for (int j = 0; j < 3; ++j) {
            float4 v = kp[j * 64 + lane];
            ks[k][j] = v;
            d += q[j].x * v.x;
            d += q[j].y * v.y;
            d += q[j].z * v.z;
            d += q[j].w * v.w;
        }
        dot[k] = d;
    }

    // Butterfly wave reduction: every lane ends with the full dot.
#pragma unroll
    for (int k = 0; k < 8; ++k) {
        float d = dot[k];
#pragma unroll
        for (int m = 1; m < 64; m <<= 1) d += __shfl_xor(d, m);
        dot[k] = d;
    }

    // Softmax over 8 (redundant per lane, cheap).
    float mx = dot[0];
#pragma unroll
    for (int k = 1; k < 8; ++k) mx = fmaxf(mx, dot[k]);
    float w[8];
    float s = 0.f;
#pragma unroll
    for (int k = 0; k < 8; ++k) { w[k] = __expf(dot[k] - mx); s += w[k]; }
    const float inv = 1.f / s;

    // out row = sum_k attn[k] * ks[k]
    float4 o[3];
#pragma unroll
    for (int j = 0; j < 3; ++j) { o[j].x = 0.f; o[j].y = 0.f; o[j].z = 0.f; o[j].w = 0.f; }
#pragma unroll
    for (int k = 0; k < 8; ++k) {
        const float a = w[k] * inv;
#pragma unroll
        for (int j = 0; j < 3; ++j) {
            o[j].x += a * ks[k][j].x;
            o[j].y += a * ks[k][j].y;
            o[j].z += a * ks[k][j].z;
            o[j].w += a * ks[k][j].w;
        }
    }

    float4* o4 = (float4*)(out + row * 768);
#pragma unroll
    for (int j = 0; j < 3; ++j) o4[j * 64 + lane] = o[j];
}

extern "C" void kernel_launch(void* const* d_in, const int* in_sizes, int n_in,
                              void* d_out, int out_size, void* d_ws, size_t ws_size,
                              hipStream_t stream) {
    const float* hidden = (const float*)d_in[0];
    const int*   sws    = (const int*)d_in[1];
    const float* w2v    = (const float*)d_in[2];
    const float* weight = (const float*)d_in[3];
    float*       out    = (float*)d_out;

    const int E = 768;
    const int M = in_sizes[0] / E;          // 8192

    // q_proj scratch: prefer d_ws; fall back to d_out (same size; attn kernel
    // reads its q row fully into registers before overwriting it).
    float* qproj = (ws_size >= (size_t)M * E * sizeof(float)) ? (float*)d_ws : out;

    dim3 ggrid(M / GM_BM, E / GM_BN);       // 64 x 12
    gemm_qproj<<<ggrid, 256, 0, stream>>>(hidden, weight, qproj, M, E, E);

    attn_fused<<<dim3(M / 4), 256, 0, stream>>>(qproj, sws, w2v, out);
}